// Round 16
// baseline (147.355 us; speedup 1.0000x reference)
//
#include <hip/hip_runtime.h>

#define B_ 8
#define T_ 4096
#define E_ 1024
#define K_ 128

typedef __bf16 bf16;
typedef bf16 bf16x8 __attribute__((ext_vector_type(8)));
typedef bf16 bf16x4 __attribute__((ext_vector_type(4)));
typedef float f32x4 __attribute__((ext_vector_type(4)));

// ---------------- K0: convert mu to bf16 ----------------
__global__ __launch_bounds__(256) void k0_cvt_mu(const float* __restrict__ mu,
                                                 bf16* __restrict__ mub) {
    int i = blockIdx.x * 256 + threadIdx.x;
    mub[i] = (bf16)mu[i];
}

// ---------------- K1 v4: full-E LDS-staged att GEMM + xb emit ----------------
// grid (T/32, B) = 1024 blocks, 256 thr (4 waves). Block: 32 t x 128 k x full E.
// Wave (tsub, khalf): 16 t x 64 k, acc[4] (~60 VGPR). k-half waves share xs via LDS
// (duplicate ds_reads are free; no duplicate HBM loads). Writes FINAL att (bf16,
// scale folded) -- no partial-sum intermediate.
__global__ __launch_bounds__(256) void k1_att(const float* __restrict__ x,
                                              const bf16* __restrict__ mub,
                                              bf16* __restrict__ att,
                                              bf16* __restrict__ xb) {
    const int b = blockIdx.y;
    const int t0 = blockIdx.x * 32;
    const int tid = threadIdx.x;
    const int w = tid >> 6, lane = tid & 63, g = lane >> 4, ln = lane & 15;
    const int tsub = w >> 1, khalf = w & 1;

    __shared__ bf16 xs[32][72];     //  4,608 B
    __shared__ bf16 ms[128][72];    // 18,432 B  (23 KB total)

    f32x4 acc[4];
#pragma unroll
    for (int m = 0; m < 4; ++m) acc[m] = (f32x4){0.f, 0.f, 0.f, 0.f};

    const int rx = tid >> 4, cx = (tid & 15) * 4;   // x-stage: 16 rows/pass, 2 passes
    const int rm = tid >> 3, cm = (tid & 7) * 8;    // mu-stage: 32 rows/pass, 4 passes

    for (int c = 0; c < 16; ++c) {
        const int ebase = c * 64;
        // stage x (fp32 -> bf16; 16 consecutive lanes = 256B segments) + emit xb
#pragma unroll
        for (int p = 0; p < 2; ++p) {
            const int row = p * 16 + rx;
            f32x4 v = *(const f32x4*)(x + ((size_t)(b * T_ + t0 + row)) * E_ + ebase + cx);
            bf16x4 o;
            o[0] = (bf16)v[0]; o[1] = (bf16)v[1]; o[2] = (bf16)v[2]; o[3] = (bf16)v[3];
            *(bf16x4*)&xs[row][cx] = o;
            *(bf16x4*)(xb + ((size_t)(b * T_ + t0 + row)) * E_ + ebase + cx) = o;
        }
        // stage mu (128B/row, full lines)
#pragma unroll
        for (int p = 0; p < 4; ++p) {
            const int row = p * 32 + rm;
            *(bf16x8*)&ms[row][cm] =
                *(const bf16x8*)(mub + (size_t)row * E_ + ebase + cm);
        }
        __syncthreads();
#pragma unroll
        for (int s = 0; s < 2; ++s) {
            const int es = s * 32 + g * 8;
            bf16x8 bf = *(const bf16x8*)&xs[tsub * 16 + ln][es];
#pragma unroll
            for (int m = 0; m < 4; ++m) {
                bf16x8 af = *(const bf16x8*)&ms[khalf * 64 + m * 16 + ln][es];
                acc[m] = __builtin_amdgcn_mfma_f32_16x16x32_bf16(af, bf, acc[m], 0, 0, 0);
            }
        }
        __syncthreads();
    }
    const int t = t0 + tsub * 16 + ln;
#pragma unroll
    for (int m = 0; m < 4; ++m)
#pragma unroll
        for (int r = 0; r < 4; ++r) {
            const int k = khalf * 64 + m * 16 + g * 4 + r;
            att[((size_t)b * K_ + k) * T_ + t] = (bf16)(acc[m][r] * 0.03125f);
        }
}

// ---------------- K2 v2: softmax on final att -> attp bf16 (1024 blocks) ----------------
__global__ __launch_bounds__(256) void k2_softmax(const bf16* __restrict__ att,
                                                  bf16* __restrict__ attp) {
    const int row = blockIdx.x;   // b*K + k
    const int tid = threadIdx.x;
    const bf16* p0 = att + (size_t)row * T_;
    float v[16];
    float m = -1e30f;
#pragma unroll
    for (int i = 0; i < 2; ++i) {
        const int off = (i * 256 + tid) * 8;
        bf16x8 a = *(const bf16x8*)(p0 + off);
#pragma unroll
        for (int j = 0; j < 8; ++j) {
            const float val = (float)a[j];
            v[i * 8 + j] = val;
            m = fmaxf(m, val);
        }
    }
#pragma unroll
    for (int off = 32; off > 0; off >>= 1) m = fmaxf(m, __shfl_xor(m, off));
    __shared__ float redm[4], reds[4];
    const int wave = tid >> 6, lane = tid & 63;
    if (lane == 0) redm[wave] = m;
    __syncthreads();
    m = fmaxf(fmaxf(redm[0], redm[1]), fmaxf(redm[2], redm[3]));
    float s = 0.f;
#pragma unroll
    for (int i = 0; i < 16; ++i) {
        v[i] = __expf(v[i] - m);
        s += v[i];
    }
#pragma unroll
    for (int off = 32; off > 0; off >>= 1) s += __shfl_xor(s, off);
    if (lane == 0) reds[wave] = s;
    __syncthreads();
    const float inv = 1.f / (reds[0] + reds[1] + reds[2] + reds[3]);
#pragma unroll
    for (int i = 0; i < 2; ++i) {
        const int off = (i * 256 + tid) * 8;
        bf16x8 o;
#pragma unroll
        for (int j = 0; j < 8; ++j) o[j] = (bf16)(v[i * 8 + j] * inv);
        *(bf16x8*)(attp + (size_t)row * T_ + off) = o;
    }
}

// ---------------- K4 v3: LDS-staged sel GEMM, 27.6 KB LDS ----------------
// grid (E/64, 8 chunks, B) = 1024 blocks, 256 thr (4 waves). [round-15 proven]
__global__ __launch_bounds__(256) void k4_sel(const bf16* __restrict__ xb,
                                              const bf16* __restrict__ attp,
                                              bf16* __restrict__ selpT) {
    const int e0 = blockIdx.x * 64;
    const int chunk = blockIdx.y;
    const int b = blockIdx.z;
    const int tid = threadIdx.x;
    const int w = tid >> 6, lane = tid & 63, g = lane >> 4, ln = lane & 15;

    __shared__ __align__(16) char smem[27648];
    bf16 (*as_)[72] = (bf16(*)[72])smem;             // attp tile [128k][64t]
    bf16 (*xs2)[72] = (bf16(*)[72])(smem + 18432);   // xb tile [64t][64e]

    f32x4 acc[8];
#pragma unroll
    for (int m = 0; m < 8; ++m) acc[m] = (f32x4){0.f, 0.f, 0.f, 0.f};

    const int rs = tid >> 3, cs = (tid & 7) * 8;

    for (int sub = 0; sub < 8; ++sub) {
        const int tc = chunk * 512 + sub * 64;
#pragma unroll
        for (int p = 0; p < 4; ++p) {
            const int row = p * 32 + rs;
            *(bf16x8*)&as_[row][cs] =
                *(const bf16x8*)(attp + ((size_t)(b * K_ + row)) * T_ + tc + cs);
        }
#pragma unroll
        for (int p = 0; p < 2; ++p) {
            const int row = p * 32 + rs;
            *(bf16x8*)&xs2[row][cs] =
                *(const bf16x8*)(xb + ((size_t)(b * T_ + tc + row)) * E_ + e0 + cs);
        }
        __syncthreads();
#pragma unroll
        for (int s = 0; s < 2; ++s) {
            const int ts = s * 32 + g * 8;
            bf16x8 bf;
#pragma unroll
            for (int j = 0; j < 8; ++j) bf[j] = xs2[ts + j][w * 16 + ln];
#pragma unroll
            for (int m = 0; m < 8; ++m) {
                bf16x8 af = *(const bf16x8*)&as_[m * 16 + ln][ts];
                acc[m] = __builtin_amdgcn_mfma_f32_16x16x32_bf16(af, bf, acc[m], 0, 0, 0);
            }
        }
        __syncthreads();
    }
    bf16 (*tlb)[136] = (bf16(*)[136])smem;
#pragma unroll
    for (int m = 0; m < 8; ++m)
#pragma unroll
        for (int r = 0; r < 4; ++r)
            tlb[w * 16 + ln][m * 16 + g * 4 + r] = (bf16)acc[m][r];
    __syncthreads();
    bf16* dst = selpT + ((size_t)chunk * B_ + b) * E_ * K_ + (size_t)e0 * K_;
#pragma unroll
    for (int rr = 0; rr < 4; ++rr) {
        const int slot = rr * 256 + tid;
        const int ee = slot >> 4;
        const int kq = slot & 15;
        bf16x8 o = *(bf16x8*)&tlb[ee][kq * 8];
        *(bf16x8*)(dst + (size_t)ee * K_ + kq * 8) = o;
    }
}

// ---------------- K4b: flat reduce over 8 chunks -> selbT bf16 [b][e][k] (512 blocks) ----
__global__ __launch_bounds__(256) void k4b_reduce(const bf16* __restrict__ selpT,
                                                  bf16* __restrict__ selbT) {
    const size_t gid = (size_t)blockIdx.x * 256 + threadIdx.x;
    const size_t f = gid * 8;
    float s[8];
#pragma unroll
    for (int j = 0; j < 8; ++j) s[j] = 0.f;
#pragma unroll
    for (int c = 0; c < 8; ++c) {
        bf16x8 v = *(const bf16x8*)(selpT + (size_t)c * (B_ * E_ * K_) + f);
#pragma unroll
        for (int j = 0; j < 8; ++j) s[j] += (float)v[j];
    }
    bf16x8 o;
#pragma unroll
    for (int j = 0; j < 8; ++j) o[j] = (bf16)s[j];
    *(bf16x8*)(selbT + f) = o;
}

// ---------------- K5: out = k*(xb + attp^T @ selbT) + b  (attp transposed in LDS) ----------
// grid (T/64, E/64, B) = 8192 blocks, 256 thr (4 waves). [round-9..15 proven]
__global__ __launch_bounds__(256) void k5_out(const bf16* __restrict__ xb,
                                              const bf16* __restrict__ attp,
                                              const bf16* __restrict__ selbT,
                                              const float* __restrict__ kp,
                                              const float* __restrict__ bp,
                                              float* __restrict__ out) {
    const int b = blockIdx.z;
    const int t0 = blockIdx.x * 64;
    const int tid = threadIdx.x;
    const int w = tid >> 6, lane = tid & 63, g = lane >> 4, ln = lane & 15;
    const int e0 = blockIdx.y * 64 + w * 16;
    const float kk = kp[0], bb = bp[0];
    __shared__ bf16 pT[64][128];   // (t,k) at pT[t][k ^ ((t&7)<<3)]

    const int u = tid & 3;
    const int kr = tid >> 2;
#pragma unroll
    for (int p = 0; p < 2; ++p) {
        const int k = p * 64 + kr;
        const bf16* src = attp + ((size_t)b * K_ + k) * T_ + t0 + u * 16;
#pragma unroll
        for (int hh = 0; hh < 2; ++hh) {
            bf16x8 v = *(const bf16x8*)(src + hh * 8);
#pragma unroll
            for (int j = 0; j < 8; ++j) {
                const int t = u * 16 + hh * 8 + j;   // t&7 == j
                pT[t][k ^ (j << 3)] = v[j];
            }
        }
    }
    __syncthreads();

    f32x4 acc[4];
#pragma unroll
    for (int m = 0; m < 4; ++m) acc[m] = (f32x4){0.f, 0.f, 0.f, 0.f};

#pragma unroll
    for (int ks = 0; ks < 4; ++ks) {
        const int k0 = ks * 32 + g * 8;
        bf16x8 bfr = *(const bf16x8*)(selbT + ((size_t)b * E_ + e0 + ln) * K_ + k0);
#pragma unroll
        for (int m = 0; m < 4; ++m) {
            const int t = m * 16 + ln;
            bf16x8 af = *(const bf16x8*)&pT[t][k0 ^ ((t & 7) << 3)];
            acc[m] = __builtin_amdgcn_mfma_f32_16x16x32_bf16(af, bfr, acc[m], 0, 0, 0);
        }
    }
#pragma unroll
    for (int m = 0; m < 4; ++m) {
#pragma unroll
        for (int r = 0; r < 4; ++r) {
            const int t = t0 + m * 16 + g * 4 + r;
            const size_t idx = ((size_t)b * T_ + t) * E_ + e0 + ln;
            out[idx] = kk * ((float)xb[idx] + acc[m][r]) + bb;
        }
    }
}

extern "C" void kernel_launch(void* const* d_in, const int* in_sizes, int n_in,
                              void* d_out, int out_size, void* d_ws, size_t ws_size,
                              hipStream_t stream) {
    const float* x  = (const float*)d_in[0];
    const float* mu = (const float*)d_in[1];
    // d_in[2]=bias, d_in[3]=Wr, d_in[4]=Wl are dead code in the reference forward.
    const float* kp = (const float*)d_in[5];
    const float* bp = (const float*)d_in[6];
    float* out = (float*)d_out;

    char* ws = (char*)d_ws;
    // Region A (16,777,216 B): att bf16 [B][K][T] (K1->K2, 8.4 MB used), then reused
    // as selpT bf16 [8][B][E][K] (K4->K4b). Stream-ordered, no overlap hazard.
    bf16*  att   = (bf16*)(ws);
    bf16*  selpT = (bf16*)(ws);
    bf16*  attp  = (bf16*)(ws + 16777216);   //  8,388,608
    bf16*  selbT = (bf16*)(ws + 25165824);   //  2,097,152
    bf16*  mub   = (bf16*)(ws + 27262976);   //    262,144
    bf16*  xb    = (bf16*)(ws + 27525120);   // 67,108,864  (total ~94.6 MB)

    k0_cvt_mu<<<dim3(512), 256, 0, stream>>>(mu, mub);
    k1_att<<<dim3(128, 8), 256, 0, stream>>>(x, mub, att, xb);
    k2_softmax<<<dim3(1024), 256, 0, stream>>>(att, attp);
    k4_sel<<<dim3(16, 8, 8), 256, 0, stream>>>(xb, attp, selpT);
    k4b_reduce<<<dim3(512), 256, 0, stream>>>(selpT, selbT);
    k5_out<<<dim3(64, 16, 8), 256, 0, stream>>>(xb, attp, selbT, kp, bp, out);
}

// Round 17
// 134.967 us; speedup vs baseline: 1.0918x; 1.0918x over previous
//
#include <hip/hip_runtime.h>

#define B_ 8
#define T_ 4096
#define E_ 1024
#define K_ 128

typedef __bf16 bf16;
typedef bf16 bf16x8 __attribute__((ext_vector_type(8)));
typedef bf16 bf16x4 __attribute__((ext_vector_type(4)));
typedef float f32x4 __attribute__((ext_vector_type(4)));

// ---------------- K0: convert mu to bf16 ----------------
__global__ __launch_bounds__(256) void k0_cvt_mu(const float* __restrict__ mu,
                                                 bf16* __restrict__ mub) {
    int i = blockIdx.x * 256 + threadIdx.x;
    mub[i] = (bf16)mu[i];
}

// ---------------- K1 v3 (round-15 proven): LDS-staged att GEMM + xb emit ----------------
// grid (T/64, 2, B) = 1024 blocks, 256 thr (4 waves). Block: 64 t x 128 k, e-half 512.
__global__ __launch_bounds__(256) void k1_att(const float* __restrict__ x,
                                              const bf16* __restrict__ mub,
                                              bf16* __restrict__ attPh,
                                              bf16* __restrict__ xb) {
    const int b = blockIdx.z;
    const int h = blockIdx.y;
    const int t0 = blockIdx.x * 64;
    const int tid = threadIdx.x;
    const int w = tid >> 6, lane = tid & 63, g = lane >> 4, ln = lane & 15;

    __shared__ bf16 xs[64][72];
    __shared__ bf16 ms[128][72];

    f32x4 acc[8];
#pragma unroll
    for (int m = 0; m < 8; ++m) acc[m] = (f32x4){0.f, 0.f, 0.f, 0.f};

    const int rx = tid >> 4, cx = (tid & 15) * 4;
    const int rm = tid >> 3, cm = (tid & 7) * 8;

    for (int c = 0; c < 8; ++c) {
        const int ebase = h * 512 + c * 64;
#pragma unroll
        for (int p = 0; p < 4; ++p) {
            const int row = p * 16 + rx;
            f32x4 v = *(const f32x4*)(x + ((size_t)(b * T_ + t0 + row)) * E_ + ebase + cx);
            bf16x4 o;
            o[0] = (bf16)v[0]; o[1] = (bf16)v[1]; o[2] = (bf16)v[2]; o[3] = (bf16)v[3];
            *(bf16x4*)&xs[row][cx] = o;
            *(bf16x4*)(xb + ((size_t)(b * T_ + t0 + row)) * E_ + ebase + cx) = o;
        }
#pragma unroll
        for (int p = 0; p < 4; ++p) {
            const int row = p * 32 + rm;
            *(bf16x8*)&ms[row][cm] =
                *(const bf16x8*)(mub + (size_t)row * E_ + ebase + cm);
        }
        __syncthreads();
#pragma unroll
        for (int s = 0; s < 2; ++s) {
            const int es = s * 32 + g * 8;
            bf16x8 bf = *(const bf16x8*)&xs[w * 16 + ln][es];
#pragma unroll
            for (int m = 0; m < 8; ++m) {
                bf16x8 af = *(const bf16x8*)&ms[m * 16 + ln][es];
                acc[m] = __builtin_amdgcn_mfma_f32_16x16x32_bf16(af, bf, acc[m], 0, 0, 0);
            }
        }
        __syncthreads();
    }
    const int t = t0 + w * 16 + ln;
#pragma unroll
    for (int m = 0; m < 8; ++m)
#pragma unroll
        for (int r = 0; r < 4; ++r)
            attPh[(((size_t)h * B_ + b) * K_ + m * 16 + g * 4 + r) * T_ + t] =
                (bf16)acc[m][r];
}

// ---------------- K2 (round-15 proven): fused half-sum + softmax -> attp bf16 ----------
__global__ __launch_bounds__(256) void k2_softmax(const bf16* __restrict__ attPh,
                                                  bf16* __restrict__ attp) {
    const int row = blockIdx.x;   // b*K + k
    const int tid = threadIdx.x;
    const bf16* p0 = attPh + (size_t)row * T_;
    const bf16* p1 = attPh + (size_t)(B_ * K_) * T_ + (size_t)row * T_;
    float v[16];
    float m = -1e30f;
#pragma unroll
    for (int i = 0; i < 2; ++i) {
        const int off = (i * 256 + tid) * 8;
        bf16x8 a = *(const bf16x8*)(p0 + off);
        bf16x8 c = *(const bf16x8*)(p1 + off);
#pragma unroll
        for (int j = 0; j < 8; ++j) {
            const float val = ((float)a[j] + (float)c[j]) * 0.03125f;
            v[i * 8 + j] = val;
            m = fmaxf(m, val);
        }
    }
#pragma unroll
    for (int off = 32; off > 0; off >>= 1) m = fmaxf(m, __shfl_xor(m, off));
    __shared__ float redm[4], reds[4];
    const int wave = tid >> 6, lane = tid & 63;
    if (lane == 0) redm[wave] = m;
    __syncthreads();
    m = fmaxf(fmaxf(redm[0], redm[1]), fmaxf(redm[2], redm[3]));
    float s = 0.f;
#pragma unroll
    for (int i = 0; i < 16; ++i) {
        v[i] = __expf(v[i] - m);
        s += v[i];
    }
#pragma unroll
    for (int off = 32; off > 0; off >>= 1) s += __shfl_xor(s, off);
    if (lane == 0) reds[wave] = s;
    __syncthreads();
    const float inv = 1.f / (reds[0] + reds[1] + reds[2] + reds[3]);
#pragma unroll
    for (int i = 0; i < 2; ++i) {
        const int off = (i * 256 + tid) * 8;
        bf16x8 o;
#pragma unroll
        for (int j = 0; j < 8; ++j) o[j] = (bf16)(v[i * 8 + j] * inv);
        *(bf16x8*)(attp + (size_t)row * T_ + off) = o;
    }
}

// ---------------- K4 v3 (round-15 proven): LDS-staged sel GEMM ----------------
__global__ __launch_bounds__(256) void k4_sel(const bf16* __restrict__ xb,
                                              const bf16* __restrict__ attp,
                                              bf16* __restrict__ selpT) {
    const int e0 = blockIdx.x * 64;
    const int chunk = blockIdx.y;
    const int b = blockIdx.z;
    const int tid = threadIdx.x;
    const int w = tid >> 6, lane = tid & 63, g = lane >> 4, ln = lane & 15;

    __shared__ __align__(16) char smem[27648];
    bf16 (*as_)[72] = (bf16(*)[72])smem;
    bf16 (*xs2)[72] = (bf16(*)[72])(smem + 18432);

    f32x4 acc[8];
#pragma unroll
    for (int m = 0; m < 8; ++m) acc[m] = (f32x4){0.f, 0.f, 0.f, 0.f};

    const int rs = tid >> 3, cs = (tid & 7) * 8;

    for (int sub = 0; sub < 8; ++sub) {
        const int tc = chunk * 512 + sub * 64;
#pragma unroll
        for (int p = 0; p < 4; ++p) {
            const int row = p * 32 + rs;
            *(bf16x8*)&as_[row][cs] =
                *(const bf16x8*)(attp + ((size_t)(b * K_ + row)) * T_ + tc + cs);
        }
#pragma unroll
        for (int p = 0; p < 2; ++p) {
            const int row = p * 32 + rs;
            *(bf16x8*)&xs2[row][cs] =
                *(const bf16x8*)(xb + ((size_t)(b * T_ + tc + row)) * E_ + e0 + cs);
        }
        __syncthreads();
#pragma unroll
        for (int s = 0; s < 2; ++s) {
            const int ts = s * 32 + g * 8;
            bf16x8 bf;
#pragma unroll
            for (int j = 0; j < 8; ++j) bf[j] = xs2[ts + j][w * 16 + ln];
#pragma unroll
            for (int m = 0; m < 8; ++m) {
                bf16x8 af = *(const bf16x8*)&as_[m * 16 + ln][ts];
                acc[m] = __builtin_amdgcn_mfma_f32_16x16x32_bf16(af, bf, acc[m], 0, 0, 0);
            }
        }
        __syncthreads();
    }
    bf16 (*tlb)[136] = (bf16(*)[136])smem;
#pragma unroll
    for (int m = 0; m < 8; ++m)
#pragma unroll
        for (int r = 0; r < 4; ++r)
            tlb[w * 16 + ln][m * 16 + g * 4 + r] = (bf16)acc[m][r];
    __syncthreads();
    bf16* dst = selpT + ((size_t)chunk * B_ + b) * E_ * K_ + (size_t)e0 * K_;
#pragma unroll
    for (int rr = 0; rr < 4; ++rr) {
        const int slot = rr * 256 + tid;
        const int ee = slot >> 4;
        const int kq = slot & 15;
        bf16x8 o = *(bf16x8*)&tlb[ee][kq * 8];
        *(bf16x8*)(dst + (size_t)ee * K_ + kq * 8) = o;
    }
}

// ---------------- K4b (round-15 proven): flat reduce -> selbT bf16 [b][e][k] ----------
__global__ __launch_bounds__(256) void k4b_reduce(const bf16* __restrict__ selpT,
                                                  bf16* __restrict__ selbT) {
    const size_t gid = (size_t)blockIdx.x * 256 + threadIdx.x;
    const size_t f = gid * 8;
    float s[8];
#pragma unroll
    for (int j = 0; j < 8; ++j) s[j] = 0.f;
#pragma unroll
    for (int c = 0; c < 8; ++c) {
        bf16x8 v = *(const bf16x8*)(selpT + (size_t)c * (B_ * E_ * K_) + f);
#pragma unroll
        for (int j = 0; j < 8; ++j) s[j] += (float)v[j];
    }
    bf16x8 o;
#pragma unroll
    for (int j = 0; j < 8; ++j) o[j] = (bf16)s[j];
    *(bf16x8*)(selbT + f) = o;
}

// ---------------- K5 v2: swapped-operand epilogue (e-major D -> f32x4 stores) ----------
// grid (T/64, E/64, B) = 8192 blocks, 256 thr (4 waves). Wave: 16 t (ln) x 64 e (m).
// A = selbT e-rows (staged in LDS), B = attp t-cols (pT, XOR-swizzled).
// D[row=e=g*4+r][col=t=ln]: lane holds 4 CONSECUTIVE e at one t -> f32x4 out store,
// bf16x4 xb residual load. 4x fewer epilogue instructions on the 134 MB out stream.
__global__ __launch_bounds__(256) void k5_out(const bf16* __restrict__ xb,
                                              const bf16* __restrict__ attp,
                                              const bf16* __restrict__ selbT,
                                              const float* __restrict__ kp,
                                              const float* __restrict__ bp,
                                              float* __restrict__ out) {
    const int b = blockIdx.z;
    const int t0 = blockIdx.x * 64;
    const int e0 = blockIdx.y * 64;
    const int tid = threadIdx.x;
    const int w = tid >> 6, lane = tid & 63, g = lane >> 4, ln = lane & 15;
    const float kk = kp[0], bb = bp[0];
    __shared__ bf16 pT[64][128];    // (t,k) at pT[t][k ^ ((t&7)<<3)], 16 KB
    __shared__ bf16 sb[64][136];    // selbT tile [64e][128k], padded, 17.4 KB

    // stage pT (proven pattern)
    {
        const int u = tid & 3;
        const int kr = tid >> 2;
#pragma unroll
        for (int p = 0; p < 2; ++p) {
            const int k = p * 64 + kr;
            const bf16* src = attp + ((size_t)b * K_ + k) * T_ + t0 + u * 16;
#pragma unroll
            for (int hh = 0; hh < 2; ++hh) {
                bf16x8 v = *(const bf16x8*)(src + hh * 8);
#pragma unroll
                for (int j = 0; j < 8; ++j) {
                    const int t = u * 16 + hh * 8 + j;   // t&7 == j
                    pT[t][k ^ (j << 3)] = v[j];
                }
            }
        }
    }
    // stage sb: 64 e-rows x 128 k (16 KB), 4 x bf16x8 per thread
    {
        const int er = tid >> 2;
        const int kc = (tid & 3) * 32;
        const bf16* src = selbT + ((size_t)b * E_ + e0 + er) * K_ + kc;
#pragma unroll
        for (int q = 0; q < 4; ++q)
            *(bf16x8*)&sb[er][kc + q * 8] = *(const bf16x8*)(src + q * 8);
    }
    __syncthreads();

    const int tl = w * 16 + ln;     // local t
    f32x4 acc[4];
#pragma unroll
    for (int m = 0; m < 4; ++m) acc[m] = (f32x4){0.f, 0.f, 0.f, 0.f};

#pragma unroll
    for (int ks = 0; ks < 4; ++ks) {
        const int k0 = ks * 32 + g * 8;
        bf16x8 bfr = *(const bf16x8*)&pT[tl][k0 ^ ((tl & 7) << 3)];
#pragma unroll
        for (int m = 0; m < 4; ++m) {
            bf16x8 af = *(const bf16x8*)&sb[m * 16 + ln][k0];
            acc[m] = __builtin_amdgcn_mfma_f32_16x16x32_bf16(af, bfr, acc[m], 0, 0, 0);
        }
    }

    const int t = t0 + tl;
#pragma unroll
    for (int m = 0; m < 4; ++m) {
        const int e = e0 + m * 16 + g * 4;
        const size_t idx = ((size_t)b * T_ + t) * E_ + e;
        bf16x4 xv = *(const bf16x4*)(xb + idx);
        f32x4 o;
        o[0] = kk * ((float)xv[0] + acc[m][0]) + bb;
        o[1] = kk * ((float)xv[1] + acc[m][1]) + bb;
        o[2] = kk * ((float)xv[2] + acc[m][2]) + bb;
        o[3] = kk * ((float)xv[3] + acc[m][3]) + bb;
        *(f32x4*)(out + idx) = o;
    }
}

extern "C" void kernel_launch(void* const* d_in, const int* in_sizes, int n_in,
                              void* d_out, int out_size, void* d_ws, size_t ws_size,
                              hipStream_t stream) {
    const float* x  = (const float*)d_in[0];
    const float* mu = (const float*)d_in[1];
    // d_in[2]=bias, d_in[3]=Wr, d_in[4]=Wl are dead code in the reference forward.
    const float* kp = (const float*)d_in[5];
    const float* bp = (const float*)d_in[6];
    float* out = (float*)d_out;

    char* ws = (char*)d_ws;
    // Region A (16,777,216 B): attPh bf16 [2][B][K][T] (K1->K2), then reused as
    // selpT bf16 [8][B][E][K] (K4->K4b). Stream-ordered, no overlap hazard.
    bf16*  attPh = (bf16*)(ws);
    bf16*  selpT = (bf16*)(ws);
    bf16*  attp  = (bf16*)(ws + 16777216);   //  8,388,608
    bf16*  selbT = (bf16*)(ws + 25165824);   //  2,097,152
    bf16*  mub   = (bf16*)(ws + 27262976);   //    262,144
    bf16*  xb    = (bf16*)(ws + 27525120);   // 67,108,864  (total ~94.6 MB)

    k0_cvt_mu<<<dim3(512), 256, 0, stream>>>(mu, mub);
    k1_att<<<dim3(64, 2, 8), 256, 0, stream>>>(x, mub, attPh, xb);
    k2_softmax<<<dim3(1024), 256, 0, stream>>>(attPh, attp);
    k4_sel<<<dim3(16, 8, 8), 256, 0, stream>>>(xb, attp, selpT);
    k4b_reduce<<<dim3(512), 256, 0, stream>>>(selpT, selbT);
    k5_out<<<dim3(64, 16, 8), 256, 0, stream>>>(xb, attp, selbT, kp, bp, out);
}